// Round 2
// baseline (16472.394 us; speedup 1.0000x reference)
//
#include <hip/hip_runtime.h>
#include <hip/hip_bf16.h>
#include <cstdint>
#include <cstddef>

// Problem constants
#define H_    128
#define IN_   86
#define OUT_  66
#define T_    50
#define B_    8192
#define NPOSE 15

// Layer-0 concatenated input: [u(86) | pad(2) | h1(128)] -> K padded to 216
#define K0PAD 216
#define NK0   54      // 216/4 float4 steps
#define NK1   64      // 256/4 float4 steps
#define A0S   220     // LDS row stride (floats), 4*odd -> 2-way bank aliasing (free)
#define A1S   260     // 4*odd
#define BR    16      // batch rows per block

// Workspace layout (float elements)
#define WP0_OFF 0
#define WP0_SZ  (NK0 * 512 * 4)          // 110592
#define WP1_OFF (WP0_OFF + WP0_SZ)
#define WP1_SZ  (NK1 * 512 * 4)          // 131072
#define WDP_OFF (WP1_OFF + WP1_SZ)       // 241664
#define WDP_SZ  (32 * 66 * 4)            // 8448
#define BS0_OFF (WDP_OFF + WDP_SZ)       // 250112
#define BS1_OFF (BS0_OFF + 512)
#define WS_TOTAL (BS1_OFF + 512)         // 251136 floats ~= 1.0 MB

__device__ __forceinline__ float sigmoid_f(float v) {
  return __fdividef(1.f, 1.f + __expf(-v));
}
__device__ __forceinline__ float tanh_f(float v) {
  float av = fabsf(v);
  float e  = __expf(-2.f * av);
  float t  = __fdividef(1.f - e, 1.f + e);
  return copysignf(t, v);
}

// NOTE: macro params must NOT be named x/y/z/w — member access (AV).w would
// get token-substituted otherwise (round-1 compile failure).
#define DOT4(AC, WV, AV)                                            \
  AC = fmaf((AV).x, (WV).x, AC); AC = fmaf((AV).y, (WV).y, AC);     \
  AC = fmaf((AV).z, (WV).z, AC); AC = fmaf((AV).w, (WV).w, AC);

// Repack kernel: weights -> [k4][512 gate-rows][4 floats] so a wave's 4
// unit-groups at consecutive units read one contiguous 64B line (16-lane
// row-broadcast on top). Also concatenates Wih|Whh along k (with pad) and
// precomputes bias sums.
__global__ void wm_prep(
    const float* __restrict__ Wih0, const float* __restrict__ Whh0,
    const float* __restrict__ bih0, const float* __restrict__ bhh0,
    const float* __restrict__ Wih1, const float* __restrict__ Whh1,
    const float* __restrict__ bih1, const float* __restrict__ bhh1,
    const float* __restrict__ Wd,
    float* __restrict__ ws)
{
  const int idx = blockIdx.x * 256 + threadIdx.x;
  if (idx < WP0_SZ) {
    const int j  = idx & 3;
    const int r  = (idx >> 2) & 511;
    const int k4 = idx >> 11;
    const int k  = k4 * 4 + j;           // 0..215
    float v = 0.f;
    if (k < IN_)       v = Wih0[r * IN_ + k];
    else if (k >= 88)  v = Whh0[r * H_ + (k - 88)];   // k in [88,216)
    ws[idx] = v;
  } else if (idx < WP1_OFF + WP1_SZ) {
    const int l  = idx - WP1_OFF;
    const int j  = l & 3;
    const int r  = (l >> 2) & 511;
    const int k4 = l >> 11;
    const int k  = k4 * 4 + j;           // 0..255
    float v = (k < H_) ? Wih1[r * H_ + k] : Whh1[r * H_ + (k - H_)];
    ws[idx] = v;
  } else if (idx < WDP_OFF + WDP_SZ) {
    const int l    = idx - WDP_OFF;
    const int j    = l & 3;
    const int rest = l >> 2;             // 0..2111
    const int o    = rest % 66;
    const int k4   = rest / 66;
    ws[idx] = Wd[o * H_ + k4 * 4 + j];
  } else if (idx < BS0_OFF + 512) {
    const int i = idx - BS0_OFF;
    ws[idx] = bih0[i] + bhh0[i];
  } else if (idx < WS_TOTAL) {
    const int i = idx - BS1_OFF;
    ws[idx] = bih1[i] + bhh1[i];
  }
}

// One LSTM layer's gates + state update for this thread's 8 units.
// Thread (row, ug): units j*16+ug, j in [0,8). 2-unit chunks for ILP.
template <int NK>
__device__ __forceinline__ void lstm_gates(
    const float* __restrict__ Wp, const float* __restrict__ bs,
    const float* aRow, int ug, float* cst, float* hout)
{
  #pragma unroll
  for (int jc = 0; jc < 4; ++jc) {
    const int u0 = (2 * jc) * 16 + ug;
    const int u1 = u0 + 16;
    float ai0 = bs[u0], af0 = bs[128 + u0], ag0 = bs[256 + u0], ao0 = bs[384 + u0];
    float ai1 = bs[u1], af1 = bs[128 + u1], ag1 = bs[256 + u1], ao1 = bs[384 + u1];
    const float4* ap = (const float4*)aRow;
    const float4* w0 = (const float4*)Wp + u0;
    const float4* w1 = (const float4*)Wp + u1;
    #pragma unroll 2
    for (int k4 = 0; k4 < NK; ++k4) {
      float4 a   = ap[k4];
      float4 wi0 = w0[0], wf0 = w0[128], wg0 = w0[256], wo0 = w0[384];
      float4 wi1 = w1[0], wf1 = w1[128], wg1 = w1[256], wo1 = w1[384];
      w0 += 512; w1 += 512;
      DOT4(ai0, wi0, a) DOT4(af0, wf0, a) DOT4(ag0, wg0, a) DOT4(ao0, wo0, a)
      DOT4(ai1, wi1, a) DOT4(af1, wf1, a) DOT4(ag1, wg1, a) DOT4(ao1, wo1, a)
    }
    {
      float ig = sigmoid_f(ai0), fg = sigmoid_f(af0);
      float gg = tanh_f(ag0),    og = sigmoid_f(ao0);
      float c  = fmaf(fg, cst[2 * jc], ig * gg);
      cst[2 * jc]  = c;
      hout[2 * jc] = og * tanh_f(c);
    }
    {
      float ig = sigmoid_f(ai1), fg = sigmoid_f(af1);
      float gg = tanh_f(ag1),    og = sigmoid_f(ao1);
      float c  = fmaf(fg, cst[2 * jc + 1], ig * gg);
      cst[2 * jc + 1]  = c;
      hout[2 * jc + 1] = og * tanh_f(c);
    }
  }
}

__global__ __launch_bounds__(256, 2) void wm_main(
    const float* __restrict__ x,
    const float* __restrict__ ws,
    const float* __restrict__ bd,
    float* __restrict__ out)
{
  const float* Wp0 = ws + WP0_OFF;
  const float* Wp1 = ws + WP1_OFF;
  const float* Wdp = ws + WDP_OFF;
  const float* bs0 = ws + BS0_OFF;
  const float* bs1 = ws + BS1_OFF;

  __shared__ float A0[BR * A0S];   // [u(86)|pad2|h1(128)] per row
  __shared__ float A1[BR * A1S];   // [h1_new(128)|h2(128)] per row

  const int tid   = threadIdx.x;
  const int row   = tid & 15;
  const int ug    = tid >> 4;                  // 0..15
  const int bglob = blockIdx.x * BR + row;

  float c1[8], c2[8], hreg[8], h2reg[8];
  #pragma unroll
  for (int j = 0; j < 8; ++j) { c1[j] = 0.f; c2[j] = 0.f; }

  for (int i = tid; i < BR * A0S; i += 256) A0[i] = 0.f;
  for (int i = tid; i < BR * A1S; i += 256) A1[i] = 0.f;
  __syncthreads();   // zero-init visible before first u-load races with it

  const float* aRow0 = A0 + row * A0S;
  const float* aRow1 = A1 + row * A1S;

  for (int t = 0; t < 65; ++t) {
    // u-load: t<50 -> x[:,t,:]. t==50 reuses x[:,49,:] already resident.
    // t>50 -> A0[0:66)=pose (written by dense), [66:86)=cond persists.
    if (t < T_) {
      const int r  = tid >> 4;
      const int lk = tid & 15;
      const float* xr = x + ((size_t)(blockIdx.x * BR + r) * T_ + t) * IN_;
      float* dst = A0 + r * A0S;
      for (int k = lk; k < IN_; k += 16) dst[k] = xr[k];
    }
    __syncthreads();

    // Layer 0: gates over [u | h1]
    lstm_gates<NK0>(Wp0, bs0, aRow0, ug, c1, hreg);
    __syncthreads();                       // everyone done reading A0/A1
    #pragma unroll
    for (int j = 0; j < 8; ++j) {
      const int u = j * 16 + ug;
      A1[row * A1S + u]      = hreg[j];    // layer-1 input slot
      A0[row * A0S + 88 + u] = hreg[j];    // next step's h1 slot
    }
    __syncthreads();

    // Layer 1: gates over [h1_new | h2_old]
    lstm_gates<NK1>(Wp1, bs1, aRow1, ug, c2, h2reg);
    __syncthreads();                       // everyone done reading old h2
    #pragma unroll
    for (int j = 0; j < 8; ++j) A1[row * A1S + 128 + j * 16 + ug] = h2reg[j];

    if (t >= T_) {
      __syncthreads();                     // h2_new visible
      const int s = t - T_;
      const float4* h2p = (const float4*)(A1 + row * A1S + 128);
      for (int o = ug; o < OUT_; o += 16) {
        float acc = bd[o];
        const float4* wp = (const float4*)Wdp + o;
        #pragma unroll 8
        for (int k4 = 0; k4 < 32; ++k4) {
          float4 a = h2p[k4];
          float4 wv = wp[(size_t)k4 * 66];
          DOT4(acc, wv, a)
        }
        out[((size_t)bglob * NPOSE + s) * OUT_ + o] = acc;
        if (s < NPOSE - 1) A0[row * A0S + o] = acc;   // next pose input
      }
    }
    __syncthreads();                       // all writes visible for next iter
  }
}

extern "C" void kernel_launch(void* const* d_in, const int* in_sizes, int n_in,
                              void* d_out, int out_size, void* d_ws, size_t ws_size,
                              hipStream_t stream)
{
  const float* x    = (const float*)d_in[0];
  const float* Wih0 = (const float*)d_in[1];
  const float* Whh0 = (const float*)d_in[2];
  const float* bih0 = (const float*)d_in[3];
  const float* bhh0 = (const float*)d_in[4];
  const float* Wih1 = (const float*)d_in[5];
  const float* Whh1 = (const float*)d_in[6];
  const float* bih1 = (const float*)d_in[7];
  const float* bhh1 = (const float*)d_in[8];
  const float* Wd   = (const float*)d_in[9];
  const float* bd   = (const float*)d_in[10];
  float* ws  = (float*)d_ws;     // needs >= ~1.0 MB
  float* out = (float*)d_out;

  wm_prep<<<WS_TOTAL / 256, 256, 0, stream>>>(Wih0, Whh0, bih0, bhh0,
                                              Wih1, Whh1, bih1, bhh1, Wd, ws);
  wm_main<<<B_ / BR, 256, 0, stream>>>(x, ws, bd, out);
}

// Round 3
// 3553.907 us; speedup vs baseline: 4.6350x; 4.6350x over previous
//
#include <hip/hip_runtime.h>
#include <hip/hip_bf16.h>
#include <cstdint>
#include <cstddef>

// Problem constants
#define H_    128
#define IN_   86
#define OUT_  66
#define T_    50
#define B_    8192
#define NPOSE 15

// MFMA-based design (round 3):
//  - block = 512 threads (8 waves), BR=32 batch rows, grid = 256 blocks (1/CU)
//  - wave (mt, nq): mt = M-tile (rows 16mt..16mt+15), nq = unit-slice
//    (units 32nq..32nq+31 across ALL 4 gates -> pointwise stays in-lane)
//  - split precision: w = w_hi + w_lo (bf16), a = a_hi + a_lo (bf16);
//    acc += ah*bh + ah*bl + al*bh  (3 MFMAs) -> ~2^-18 rel, fp32-quality
//  - weights prepacked in ws in exact per-lane fragment order:
//    b_frag[lane][j] = W[nt*16 + (lane&15)][kt*32 + (lane>>4)*8 + j]
//    layout: [ktile][ntile][hi|lo][lane][8 bf16] -> 1KB contiguous per half
// K0 = 224: [u(86) | zero-pad(10) | h1(128)] ; K1 = 256: [h1 | h2]
#define K0T 7
#define K1T 8
#define KDT 4
#define NT0 32
#define NT1 32
#define NTD 5
#define S0  224   // A0 row stride in bf16 elems (448B, 16B-mult)
#define S1  264   // A1 row stride (528B, 16B-mult)
#define BR  32

// ws layout (bytes)
#define B0P_OFF 0
#define B0P_SZ  (K0T * NT0 * 2 * 1024)   // 458752
#define B1P_OFF (B0P_OFF + B0P_SZ)
#define B1P_SZ  (K1T * NT1 * 2 * 1024)   // 524288
#define BDP_OFF (B1P_OFF + B1P_SZ)       // 983040
#define BDP_SZ  (KDT * NTD * 2 * 1024)   // 40960
#define WS_BYTES (BDP_OFF + BDP_SZ)      // 1024000
// element counts (ushort)
#define B0P_N (B0P_SZ / 2)               // 229376
#define B1P_N (B1P_SZ / 2)               // 262144
#define TOT_N ((B0P_SZ + B1P_SZ + BDP_SZ) / 2)  // 512000

typedef __attribute__((ext_vector_type(8))) short bfrag;
typedef __attribute__((ext_vector_type(4))) float ffrag;

#define MFMA(AC, AA, BB) \
  AC = __builtin_amdgcn_mfma_f32_16x16x32_bf16((AA), (BB), (AC), 0, 0, 0)

__device__ __forceinline__ unsigned short bf16rn(float f) {
  union { float f; unsigned int u; } cv; cv.f = f;
  unsigned int u = cv.u;
  u += 0x7FFFu + ((u >> 16) & 1u);   // round-to-nearest-even
  return (unsigned short)(u >> 16);
}
__device__ __forceinline__ float bf16tof(unsigned short h) {
  union { unsigned int u; float f; } cv; cv.u = ((unsigned int)h) << 16;
  return cv.f;
}
__device__ __forceinline__ float sigmoid_f(float v) {
  return __fdividef(1.f, 1.f + __expf(-v));
}
__device__ __forceinline__ float tanh_f(float v) {
  float av = fabsf(v);
  float e  = __expf(-2.f * av);
  float t  = __fdividef(1.f - e, 1.f + e);
  return copysignf(t, v);
}

// ---------------- prep: pack weights into MFMA fragment order (hi/lo) -------
__global__ void wm_prep(
    const float* __restrict__ Wih0, const float* __restrict__ Whh0,
    const float* __restrict__ Wih1, const float* __restrict__ Whh1,
    const float* __restrict__ Wd,
    unsigned short* __restrict__ wsu)
{
  const int idx = blockIdx.x * 256 + threadIdx.x;
  if (idx >= TOT_N) return;
  int region, l;
  if (idx < B0P_N)               { region = 0; l = idx; }
  else if (idx < B0P_N + B1P_N)  { region = 1; l = idx - B0P_N; }
  else                           { region = 2; l = idx - (B0P_N + B1P_N); }

  int k, nt, hl, lane, j;
  if (region < 2) {
    k  = l >> 15;            // 32*2*512 = 32768 per ktile
    int r1 = l & 32767;
    nt = r1 >> 10;
    int r2 = r1 & 1023;
    hl = r2 >> 9;
    int li = r2 & 511;
    lane = li >> 3; j = li & 7;
  } else {
    k  = l / 5120;           // 5*2*512 per ktile
    int r1 = l % 5120;
    nt = r1 >> 10;
    int r2 = r1 & 1023;
    hl = r2 >> 9;
    int li = r2 & 511;
    lane = li >> 3; j = li & 7;
  }
  const int n  = nt * 16 + (lane & 15);
  const int kk = k * 32 + (lane >> 4) * 8 + j;

  float v = 0.f;
  if (region == 0) {
    if (kk < IN_)                    v = Wih0[n * IN_ + kk];
    else if (kk >= 96 && kk < 224)   v = Whh0[n * H_ + (kk - 96)];
  } else if (region == 1) {
    v = (kk < H_) ? Wih1[n * H_ + kk] : Whh1[n * H_ + (kk - H_)];
  } else {
    if (n < OUT_)                    v = Wd[n * H_ + kk];
  }
  const unsigned short hi = bf16rn(v);
  unsigned short outv = hi;
  if (hl == 1) outv = bf16rn(v - bf16tof(hi));
  wsu[idx] = outv;
}

// ---------------- main persistent-recurrence kernel --------------------------
__global__ __launch_bounds__(512, 2) void wm_main(
    const float* __restrict__ x,
    const char*  __restrict__ wsb,
    const float* __restrict__ bih0, const float* __restrict__ bhh0,
    const float* __restrict__ bih1, const float* __restrict__ bhh1,
    const float* __restrict__ bd,
    float* __restrict__ out)
{
  __shared__ __align__(16) unsigned short A0h[BR * S0];
  __shared__ __align__(16) unsigned short A0l[BR * S0];
  __shared__ __align__(16) unsigned short A1h[BR * S1];
  __shared__ __align__(16) unsigned short A1l[BR * S1];

  const int tid  = threadIdx.x;
  const int lane = tid & 63;
  const int wv   = tid >> 6;
  const int mt   = wv & 1;        // M-tile: rows 16mt..16mt+15
  const int nq   = wv >> 1;       // unit slice: units 32nq..32nq+31
  const int ln15 = lane & 15;
  const int quad = lane >> 4;
  const int lane16 = lane * 16;

  const char* B0 = wsb + B0P_OFF;
  const char* B1 = wsb + B1P_OFF;
  const char* BD = wsb + BDP_OFF;

  // zero LDS (h/c state zero-init; pad region [86,96) stays zero forever)
  for (int i = tid; i < BR * S0; i += 512) { A0h[i] = 0; A0l[i] = 0; }
  for (int i = tid; i < BR * S1; i += 512) { A1h[i] = 0; A1l[i] = 0; }

  // bias preload (constant across steps) — lane's unit col = ln15
  float b0r[2][4], b1r[2][4];
  #pragma unroll
  for (int uh = 0; uh < 2; ++uh)
    #pragma unroll
    for (int g = 0; g < 4; ++g) {
      const int n = g * 128 + nq * 32 + uh * 16 + ln15;
      b0r[uh][g] = bih0[n] + bhh0[n];
      b1r[uh][g] = bih1[n] + bhh1[n];
    }
  // dense tiles per wave: wave0 -> {0,1}, wave1 -> {2}, wave2 -> {3}, wave3 -> {4}
  const int dnt0 = (nq == 0) ? 0 : (nq + 1);
  const int ndt  = (nq == 0) ? 2 : 1;
  float bdr[2];
  #pragma unroll
  for (int d = 0; d < 2; ++d) {
    const int o = (dnt0 + d) * 16 + ln15;
    bdr[d] = (d < ndt && o < OUT_) ? bd[o] : 0.f;
  }

  float c1[2][4], c2[2][4];
  #pragma unroll
  for (int uh = 0; uh < 2; ++uh)
    #pragma unroll
    for (int r = 0; r < 4; ++r) { c1[uh][r] = 0.f; c2[uh][r] = 0.f; }

  const int arow  = mt * 16 + ln15;              // A-fragment row (this wave)
  const int a0off = arow * S0 + quad * 8;
  const int a1off = arow * S1 + quad * 8;
  const int prow  = mt * 16 + quad * 4;          // C/D rows = prow + reg
  const int unitb = nq * 32 + ln15;              // unit col base (uh adds 16)

  __syncthreads();

  for (int t = 0; t < 65; ++t) {
    // ---- input staging: t<50 from x; t==50 reuses x[:,49,:]; t>50 pose+cond
    if (t < T_) {
      const int r  = tid >> 4;
      const int kk = tid & 15;
      const float* xr = x + ((size_t)(blockIdx.x * BR + r) * T_ + t) * IN_;
      for (int k = kk; k < IN_; k += 16) {
        const float v = xr[k];
        const unsigned short hi = bf16rn(v);
        A0h[r * S0 + k] = hi;
        A0l[r * S0 + k] = bf16rn(v - bf16tof(hi));
      }
    }
    __syncthreads();   // (A) input + prev pose visible

    // ---- layer 0 GEMM: gates0 = [u|h1] x W0^T, acc init = bias
    ffrag acc0[2][4];
    #pragma unroll
    for (int uh = 0; uh < 2; ++uh)
      #pragma unroll
      for (int g = 0; g < 4; ++g) {
        const float b = b0r[uh][g];
        acc0[uh][g] = (ffrag){b, b, b, b};
      }
    #pragma unroll 2
    for (int k = 0; k < K0T; ++k) {
      const bfrag ah = *(const bfrag*)(A0h + a0off + k * 32);
      const bfrag al = *(const bfrag*)(A0l + a0off + k * 32);
      #pragma unroll
      for (int uh = 0; uh < 2; ++uh)
        #pragma unroll
        for (int g = 0; g < 4; ++g) {
          const int nt = g * 8 + nq * 2 + uh;
          const char* bp = B0 + (size_t)(k * NT0 + nt) * 2048 + lane16;
          const bfrag bh = *(const bfrag*)bp;
          const bfrag bl = *(const bfrag*)(bp + 1024);
          MFMA(acc0[uh][g], ah, bh);
          MFMA(acc0[uh][g], ah, bl);
          MFMA(acc0[uh][g], al, bh);
        }
    }
    __syncthreads();   // (B) all waves done reading A0/A1 h1 regions

    // ---- layer 0 pointwise: all 4 gates in-lane; write h1 hi/lo
    #pragma unroll
    for (int uh = 0; uh < 2; ++uh) {
      const int unit = unitb + uh * 16;
      #pragma unroll
      for (int r = 0; r < 4; ++r) {
        const float ig = sigmoid_f(acc0[uh][0][r]);
        const float fg = sigmoid_f(acc0[uh][1][r]);
        const float gg = tanh_f(acc0[uh][2][r]);
        const float og = sigmoid_f(acc0[uh][3][r]);
        const float c  = fmaf(fg, c1[uh][r], ig * gg);
        c1[uh][r] = c;
        const float h  = og * tanh_f(c);
        const unsigned short hi = bf16rn(h);
        const unsigned short lo = bf16rn(h - bf16tof(hi));
        const int row = prow + r;
        A0h[row * S0 + 96 + unit] = hi;  A0l[row * S0 + 96 + unit] = lo;
        A1h[row * S1 + unit]      = hi;  A1l[row * S1 + unit]      = lo;
      }
    }
    __syncthreads();   // (C) h1 visible

    // ---- layer 1 GEMM: gates1 = [h1|h2] x W1^T
    ffrag acc1[2][4];
    #pragma unroll
    for (int uh = 0; uh < 2; ++uh)
      #pragma unroll
      for (int g = 0; g < 4; ++g) {
        const float b = b1r[uh][g];
        acc1[uh][g] = (ffrag){b, b, b, b};
      }
    #pragma unroll 2
    for (int k = 0; k < K1T; ++k) {
      const bfrag ah = *(const bfrag*)(A1h + a1off + k * 32);
      const bfrag al = *(const bfrag*)(A1l + a1off + k * 32);
      #pragma unroll
      for (int uh = 0; uh < 2; ++uh)
        #pragma unroll
        for (int g = 0; g < 4; ++g) {
          const int nt = g * 8 + nq * 2 + uh;
          const char* bp = B1 + (size_t)(k * NT1 + nt) * 2048 + lane16;
          const bfrag bh = *(const bfrag*)bp;
          const bfrag bl = *(const bfrag*)(bp + 1024);
          MFMA(acc1[uh][g], ah, bh);
          MFMA(acc1[uh][g], ah, bl);
          MFMA(acc1[uh][g], al, bh);
        }
    }
    __syncthreads();   // (D) all waves done reading A1 h2 region

    // ---- layer 1 pointwise: write h2 hi/lo
    #pragma unroll
    for (int uh = 0; uh < 2; ++uh) {
      const int unit = unitb + uh * 16;
      #pragma unroll
      for (int r = 0; r < 4; ++r) {
        const float ig = sigmoid_f(acc1[uh][0][r]);
        const float fg = sigmoid_f(acc1[uh][1][r]);
        const float gg = tanh_f(acc1[uh][2][r]);
        const float og = sigmoid_f(acc1[uh][3][r]);
        const float c  = fmaf(fg, c2[uh][r], ig * gg);
        c2[uh][r] = c;
        const float h  = og * tanh_f(c);
        const unsigned short hi = bf16rn(h);
        const unsigned short lo = bf16rn(h - bf16tof(hi));
        const int row = prow + r;
        A1h[row * S1 + 128 + unit] = hi;  A1l[row * S1 + 128 + unit] = lo;
      }
    }

    // ---- dense head + pose feedback (t >= 50)
    if (t >= T_) {
      __syncthreads();   // (E) new h2 visible
      const int s = t - T_;
      ffrag dacc[2];
      #pragma unroll
      for (int d = 0; d < 2; ++d) dacc[d] = (ffrag){bdr[d], bdr[d], bdr[d], bdr[d]};
      #pragma unroll
      for (int k = 0; k < KDT; ++k) {
        const bfrag ah = *(const bfrag*)(A1h + a1off + 128 + k * 32);
        const bfrag al = *(const bfrag*)(A1l + a1off + 128 + k * 32);
        for (int d = 0; d < ndt; ++d) {
          const char* bp = BD + (size_t)(k * NTD + dnt0 + d) * 2048 + lane16;
          const bfrag bh = *(const bfrag*)bp;
          const bfrag bl = *(const bfrag*)(bp + 1024);
          MFMA(dacc[d], ah, bh);
          MFMA(dacc[d], ah, bl);
          MFMA(dacc[d], al, bh);
        }
      }
      for (int d = 0; d < ndt; ++d) {
        const int o = (dnt0 + d) * 16 + ln15;
        if (o < OUT_) {
          #pragma unroll
          for (int r = 0; r < 4; ++r) {
            const int row = prow + r;
            const float v = dacc[d][r];
            out[((size_t)(blockIdx.x * BR + row) * NPOSE + s) * OUT_ + o] = v;
            if (s < NPOSE - 1) {
              const unsigned short hi = bf16rn(v);
              A0h[row * S0 + o] = hi;
              A0l[row * S0 + o] = bf16rn(v - bf16tof(hi));
            }
          }
        }
      }
    }
    __syncthreads();   // (F) tail: pose/h2 writes settle before next iter
  }
}

extern "C" void kernel_launch(void* const* d_in, const int* in_sizes, int n_in,
                              void* d_out, int out_size, void* d_ws, size_t ws_size,
                              hipStream_t stream)
{
  const float* x    = (const float*)d_in[0];
  const float* Wih0 = (const float*)d_in[1];
  const float* Whh0 = (const float*)d_in[2];
  const float* bih0 = (const float*)d_in[3];
  const float* bhh0 = (const float*)d_in[4];
  const float* Wih1 = (const float*)d_in[5];
  const float* Whh1 = (const float*)d_in[6];
  const float* bih1 = (const float*)d_in[7];
  const float* bhh1 = (const float*)d_in[8];
  const float* Wd   = (const float*)d_in[9];
  const float* bd   = (const float*)d_in[10];

  wm_prep<<<TOT_N / 256, 256, 0, stream>>>(Wih0, Whh0, Wih1, Whh1, Wd,
                                           (unsigned short*)d_ws);
  wm_main<<<B_ / BR, 512, 0, stream>>>(x, (const char*)d_ws,
                                       bih0, bhh0, bih1, bhh1, bd,
                                       (float*)d_out);
}

// Round 4
// 2299.035 us; speedup vs baseline: 7.1649x; 1.5458x over previous
//
#include <hip/hip_runtime.h>
#include <hip/hip_bf16.h>
#include <cstdint>
#include <cstddef>

// Problem constants
#define H_    128
#define IN_   86
#define OUT_  66
#define T_    50
#define B_    8192
#define NPOSE 15

// Round-4 design: dedup weight stream.
//  - block = 512 threads (8 waves), BR=32 rows, grid = 256 (1 block/CU)
//  - wave w (0..7) owns unit slice w*16..w*16+15 across ALL 4 gates
//    (ntile(g) = g*8 + w) and ALL 32 rows (two A-frags).
//    => every B-tile read exactly once per block per step (round-3 read each
//    twice via mt-duplicated waves) and each B-frag feeds 2 MFMAs.
//  - split precision: acc += ah*bh + al*bh + ah*bl (3 MFMAs, fp32-quality)
//  - S0 = 232 ushorts (116 dwords = 4*odd): A-frag ds_read_b128 lane-stride
//    hits 8 bank-groups -> 2-way aliasing (free). Round-3 S0=224 was 8-way.
// K0 = 224: [u(86) | zero-pad(10) | h1(128)] ; K1 = 256: [h1 | h2]
#define K0T 7
#define K1T 8
#define KDT 4
#define NT0 32
#define NT1 32
#define NTD 5
#define S0  232   // A0 row stride in bf16 elems (464 B, 16B-mult, 4*odd dwords)
#define S1  264   // A1 row stride (528 B, 132 dwords = 4*odd)
#define BR  32

// ws layout (bytes) — packed B fragments: [ktile][ntile][hi|lo][lane][8 bf16]
#define B0P_OFF 0
#define B0P_SZ  (K0T * NT0 * 2 * 1024)   // 458752
#define B1P_OFF (B0P_OFF + B0P_SZ)
#define B1P_SZ  (K1T * NT1 * 2 * 1024)   // 524288
#define BDP_OFF (B1P_OFF + B1P_SZ)       // 983040
#define BDP_SZ  (KDT * NTD * 2 * 1024)   // 40960
#define B0P_N (B0P_SZ / 2)
#define B1P_N (B1P_SZ / 2)
#define TOT_N ((B0P_SZ + B1P_SZ + BDP_SZ) / 2)

typedef __attribute__((ext_vector_type(8))) short bfrag;
typedef __attribute__((ext_vector_type(4))) float ffrag;

#define MFMA(AC, AA, BB) \
  AC = __builtin_amdgcn_mfma_f32_16x16x32_bf16((AA), (BB), (AC), 0, 0, 0)

__device__ __forceinline__ unsigned short bf16rn(float f) {
  union { float f; unsigned int u; } cv; cv.f = f;
  unsigned int u = cv.u;
  u += 0x7FFFu + ((u >> 16) & 1u);   // round-to-nearest-even
  return (unsigned short)(u >> 16);
}
__device__ __forceinline__ float bf16tof(unsigned short h) {
  union { unsigned int u; float f; } cv; cv.u = ((unsigned int)h) << 16;
  return cv.f;
}
__device__ __forceinline__ float sigmoid_f(float v) {
  return __fdividef(1.f, 1.f + __expf(-v));
}
__device__ __forceinline__ float tanh_f(float v) {
  float av = fabsf(v);
  float e  = __expf(-2.f * av);
  float t  = __fdividef(1.f - e, 1.f + e);
  return copysignf(t, v);
}

// ---------------- prep: pack weights into MFMA fragment order (hi/lo) -------
__global__ void wm_prep(
    const float* __restrict__ Wih0, const float* __restrict__ Whh0,
    const float* __restrict__ Wih1, const float* __restrict__ Whh1,
    const float* __restrict__ Wd,
    unsigned short* __restrict__ wsu)
{
  const int idx = blockIdx.x * 256 + threadIdx.x;
  if (idx >= TOT_N) return;
  int region, l;
  if (idx < B0P_N)               { region = 0; l = idx; }
  else if (idx < B0P_N + B1P_N)  { region = 1; l = idx - B0P_N; }
  else                           { region = 2; l = idx - (B0P_N + B1P_N); }

  int k, nt, hl, lane, j;
  if (region < 2) {
    k  = l >> 15;            // 32*2*512 = 32768 ushorts per ktile
    int r1 = l & 32767;
    nt = r1 >> 10;
    int r2 = r1 & 1023;
    hl = r2 >> 9;
    int li = r2 & 511;
    lane = li >> 3; j = li & 7;
  } else {
    k  = l / 5120;           // 5*2*512 per ktile
    int r1 = l % 5120;
    nt = r1 >> 10;
    int r2 = r1 & 1023;
    hl = r2 >> 9;
    int li = r2 & 511;
    lane = li >> 3; j = li & 7;
  }
  const int n  = nt * 16 + (lane & 15);
  const int kk = k * 32 + (lane >> 4) * 8 + j;

  float v = 0.f;
  if (region == 0) {
    if (kk < IN_)                    v = Wih0[n * IN_ + kk];
    else if (kk >= 96 && kk < 224)   v = Whh0[n * H_ + (kk - 96)];
  } else if (region == 1) {
    v = (kk < H_) ? Wih1[n * H_ + kk] : Whh1[n * H_ + (kk - H_)];
  } else {
    if (n < OUT_)                    v = Wd[n * H_ + kk];
  }
  const unsigned short hi = bf16rn(v);
  unsigned short outv = hi;
  if (hl == 1) outv = bf16rn(v - bf16tof(hi));
  wsu[idx] = outv;
}

// ---------------- main persistent-recurrence kernel --------------------------
__global__ __launch_bounds__(512, 2) void wm_main(
    const float* __restrict__ x,
    const char*  __restrict__ wsb,
    const float* __restrict__ bih0, const float* __restrict__ bhh0,
    const float* __restrict__ bih1, const float* __restrict__ bhh1,
    const float* __restrict__ bd,
    float* __restrict__ out)
{
  __shared__ __align__(16) unsigned short A0h[BR * S0];
  __shared__ __align__(16) unsigned short A0l[BR * S0];
  __shared__ __align__(16) unsigned short A1h[BR * S1];
  __shared__ __align__(16) unsigned short A1l[BR * S1];

  const int tid  = threadIdx.x;
  const int lane = tid & 63;
  const int wv   = tid >> 6;      // wave id = unit-slice id (0..7)
  const int ln15 = lane & 15;
  const int quad = lane >> 4;
  const int lane16 = lane * 16;

  const char* B0 = wsb + B0P_OFF;
  const char* B1 = wsb + B1P_OFF;
  const char* BD = wsb + BDP_OFF;

  // zero LDS (h/c zero-init; A0 pad [86,96) and [224,232) stay zero forever)
  for (int i = tid; i < BR * S0; i += 512) { A0h[i] = 0; A0l[i] = 0; }
  for (int i = tid; i < BR * S1; i += 512) { A1h[i] = 0; A1l[i] = 0; }

  // bias preload — this wave's unit col = wv*16 + ln15, per gate g
  float b0r[4], b1r[4];
  #pragma unroll
  for (int g = 0; g < 4; ++g) {
    const int n = g * 128 + wv * 16 + ln15;
    b0r[g] = bih0[n] + bhh0[n];
    b1r[g] = bih1[n] + bhh1[n];
  }
  // dense head: waves 0..4 own dtile = wv (o = wv*16 + ln15)
  const int od = wv * 16 + ln15;
  const float bdr = (wv < NTD && od < OUT_) ? bd[od] : 0.f;

  float c1[2][4], c2[2][4];
  #pragma unroll
  for (int m = 0; m < 2; ++m)
    #pragma unroll
    for (int r = 0; r < 4; ++r) { c1[m][r] = 0.f; c2[m][r] = 0.f; }

  // A-fragment LDS offsets for the two M-tiles (rows ln15 and 16+ln15)
  const int a0b0 = ln15 * S0 + quad * 8;
  const int a0b1 = (16 + ln15) * S0 + quad * 8;
  const int a1b0 = ln15 * S1 + quad * 8;
  const int a1b1 = (16 + ln15) * S1 + quad * 8;
  const int prow = quad * 4;               // C/D rows = m*16 + prow + r
  const int unit = wv * 16 + ln15;         // this lane's unit column

  __syncthreads();

  for (int t = 0; t < 65; ++t) {
    // ---- input staging: t<50 from x; t==50 reuses x[:,49,:]; t>50 pose+cond
    if (t < T_) {
      const int r  = tid >> 4;
      const int kk = tid & 15;
      const float* xr = x + ((size_t)(blockIdx.x * BR + r) * T_ + t) * IN_;
      for (int k = kk; k < IN_; k += 16) {
        const float v = xr[k];
        const unsigned short hi = bf16rn(v);
        A0h[r * S0 + k] = hi;
        A0l[r * S0 + k] = bf16rn(v - bf16tof(hi));
      }
    }
    __syncthreads();   // (A) input/pose visible

    // ---- layer 0 GEMM: gates0 = [u|h1] x W0^T  (acc init = bias)
    ffrag acc0[4][2];
    #pragma unroll
    for (int g = 0; g < 4; ++g) {
      acc0[g][0] = (ffrag){b0r[g], b0r[g], b0r[g], b0r[g]};
      acc0[g][1] = acc0[g][0];
    }
    #pragma unroll 2
    for (int k = 0; k < K0T; ++k) {
      const bfrag ah0 = *(const bfrag*)(A0h + a0b0 + k * 32);
      const bfrag al0 = *(const bfrag*)(A0l + a0b0 + k * 32);
      const bfrag ah1 = *(const bfrag*)(A0h + a0b1 + k * 32);
      const bfrag al1 = *(const bfrag*)(A0l + a0b1 + k * 32);
      #pragma unroll
      for (int g = 0; g < 4; ++g) {
        const char* bp = B0 + (size_t)(k * NT0 + g * 8 + wv) * 2048 + lane16;
        const bfrag bh = *(const bfrag*)bp;
        const bfrag bl = *(const bfrag*)(bp + 1024);
        MFMA(acc0[g][0], ah0, bh);
        MFMA(acc0[g][1], ah1, bh);
        MFMA(acc0[g][0], al0, bh);
        MFMA(acc0[g][1], al1, bh);
        MFMA(acc0[g][0], ah0, bl);
        MFMA(acc0[g][1], ah1, bl);
      }
    }
    __syncthreads();   // (B) all waves done reading A0

    // ---- layer 0 pointwise: all 4 gates in-lane; write h1 hi/lo
    #pragma unroll
    for (int m = 0; m < 2; ++m)
      #pragma unroll
      for (int r = 0; r < 4; ++r) {
        const float ig = sigmoid_f(acc0[0][m][r]);
        const float fg = sigmoid_f(acc0[1][m][r]);
        const float gg = tanh_f(acc0[2][m][r]);
        const float og = sigmoid_f(acc0[3][m][r]);
        const float c  = fmaf(fg, c1[m][r], ig * gg);
        c1[m][r] = c;
        const float h  = og * tanh_f(c);
        const unsigned short hi = bf16rn(h);
        const unsigned short lo = bf16rn(h - bf16tof(hi));
        const int row = m * 16 + prow + r;
        A0h[row * S0 + 96 + unit] = hi;  A0l[row * S0 + 96 + unit] = lo;
        A1h[row * S1 + unit]      = hi;  A1l[row * S1 + unit]      = lo;
      }
    __syncthreads();   // (C) h1 visible

    // ---- layer 1 GEMM: gates1 = [h1|h2] x W1^T
    ffrag acc1[4][2];
    #pragma unroll
    for (int g = 0; g < 4; ++g) {
      acc1[g][0] = (ffrag){b1r[g], b1r[g], b1r[g], b1r[g]};
      acc1[g][1] = acc1[g][0];
    }
    #pragma unroll 2
    for (int k = 0; k < K1T; ++k) {
      const bfrag ah0 = *(const bfrag*)(A1h + a1b0 + k * 32);
      const bfrag al0 = *(const bfrag*)(A1l + a1b0 + k * 32);
      const bfrag ah1 = *(const bfrag*)(A1h + a1b1 + k * 32);
      const bfrag al1 = *(const bfrag*)(A1l + a1b1 + k * 32);
      #pragma unroll
      for (int g = 0; g < 4; ++g) {
        const char* bp = B1 + (size_t)(k * NT1 + g * 8 + wv) * 2048 + lane16;
        const bfrag bh = *(const bfrag*)bp;
        const bfrag bl = *(const bfrag*)(bp + 1024);
        MFMA(acc1[g][0], ah0, bh);
        MFMA(acc1[g][1], ah1, bh);
        MFMA(acc1[g][0], al0, bh);
        MFMA(acc1[g][1], al1, bh);
        MFMA(acc1[g][0], ah0, bl);
        MFMA(acc1[g][1], ah1, bl);
      }
    }
    __syncthreads();   // (D) all waves done reading A1 (old h2)

    // ---- layer 1 pointwise: write h2 hi/lo
    #pragma unroll
    for (int m = 0; m < 2; ++m)
      #pragma unroll
      for (int r = 0; r < 4; ++r) {
        const float ig = sigmoid_f(acc1[0][m][r]);
        const float fg = sigmoid_f(acc1[1][m][r]);
        const float gg = tanh_f(acc1[2][m][r]);
        const float og = sigmoid_f(acc1[3][m][r]);
        const float c  = fmaf(fg, c2[m][r], ig * gg);
        c2[m][r] = c;
        const float h  = og * tanh_f(c);
        const unsigned short hi = bf16rn(h);
        const unsigned short lo = bf16rn(h - bf16tof(hi));
        const int row = m * 16 + prow + r;
        A1h[row * S1 + 128 + unit] = hi;  A1l[row * S1 + 128 + unit] = lo;
      }

    // ---- dense head + pose feedback (t >= 50)
    if (t >= T_) {
      __syncthreads();   // (E) new h2 visible
      const int s = t - T_;
      if (wv < NTD) {
        ffrag dacc[2];
        dacc[0] = (ffrag){bdr, bdr, bdr, bdr};
        dacc[1] = dacc[0];
        #pragma unroll
        for (int k = 0; k < KDT; ++k) {
          const bfrag ah0 = *(const bfrag*)(A1h + a1b0 + 128 + k * 32);
          const bfrag al0 = *(const bfrag*)(A1l + a1b0 + 128 + k * 32);
          const bfrag ah1 = *(const bfrag*)(A1h + a1b1 + 128 + k * 32);
          const bfrag al1 = *(const bfrag*)(A1l + a1b1 + 128 + k * 32);
          const char* bp = BD + (size_t)(k * NTD + wv) * 2048 + lane16;
          const bfrag bh = *(const bfrag*)bp;
          const bfrag bl = *(const bfrag*)(bp + 1024);
          MFMA(dacc[0], ah0, bh);
          MFMA(dacc[1], ah1, bh);
          MFMA(dacc[0], al0, bh);
          MFMA(dacc[1], al1, bh);
          MFMA(dacc[0], ah0, bl);
          MFMA(dacc[1], ah1, bl);
        }
        if (od < OUT_) {
          #pragma unroll
          for (int m = 0; m < 2; ++m)
            #pragma unroll
            for (int r = 0; r < 4; ++r) {
              const int row = m * 16 + prow + r;
              const float v = dacc[m][r];
              out[((size_t)(blockIdx.x * BR + row) * NPOSE + s) * OUT_ + od] = v;
              if (s < NPOSE - 1) {
                const unsigned short hi = bf16rn(v);
                A0h[row * S0 + od] = hi;
                A0l[row * S0 + od] = bf16rn(v - bf16tof(hi));
              }
            }
        }
      }
    }
    __syncthreads();   // (F) pose/h2 writes settle before next iter
  }
}

extern "C" void kernel_launch(void* const* d_in, const int* in_sizes, int n_in,
                              void* d_out, int out_size, void* d_ws, size_t ws_size,
                              hipStream_t stream)
{
  const float* x    = (const float*)d_in[0];
  const float* Wih0 = (const float*)d_in[1];
  const float* Whh0 = (const float*)d_in[2];
  const float* bih0 = (const float*)d_in[3];
  const float* bhh0 = (const float*)d_in[4];
  const float* Wih1 = (const float*)d_in[5];
  const float* Whh1 = (const float*)d_in[6];
  const float* bih1 = (const float*)d_in[7];
  const float* bhh1 = (const float*)d_in[8];
  const float* Wd   = (const float*)d_in[9];
  const float* bd   = (const float*)d_in[10];

  wm_prep<<<(TOT_N + 255) / 256, 256, 0, stream>>>(Wih0, Whh0, Wih1, Whh1, Wd,
                                                   (unsigned short*)d_ws);
  wm_main<<<B_ / BR, 512, 0, stream>>>(x, (const char*)d_ws,
                                       bih0, bhh0, bih1, bhh1, bd,
                                       (float*)d_out);
}

// Round 5
// 1716.796 us; speedup vs baseline: 9.5948x; 1.3391x over previous
//
#include <hip/hip_runtime.h>
#include <hip/hip_bf16.h>
#include <cstdint>
#include <cstddef>

// Problem constants
#define H_    128
#define IN_   86
#define OUT_  66
#define T_    50
#define B_    8192
#define NPOSE 15

// Round-5 design: occupancy x2 + hi-only weights.
//  - BR=16 rows/block, grid=512 (2 blocks/CU), 8 waves/block -> 16 waves/CU
//    (4/SIMD, __launch_bounds__(512,4) caps VGPR at 128).
//  - wave w owns unit slice w*16..w*16+15 across ALL 4 gates (ntile = g*8+w),
//    one M-tile (16 rows). Pointwise fully in-lane.
//  - precision: weights bf16-hi ONLY; activations split hi/lo:
//    acc += ah*bh + al*bh (2 MFMAs). Error model: gate preact ~7e-4,
//    damped by recurrence -> predicted absmax 1.5-2.5e-3 (< 4.08e-3 thr).
//  - B-frags packed [ktile][ntile][lane][8bf16] = 1KB/tile, read once/block.
// K0 = 224: [u(86)|pad(10)|h1(128)] ; K1 = 256: [h1|h2]
#define K0T 7
#define K1T 8
#define KDT 4
#define NT0 32
#define NT1 32
#define NTD 5
#define S0  232   // A0 row stride (ushorts); 116 dwords = 4*odd (2-way, free)
#define S1  264   // A1 row stride; 132 dwords = 4*odd
#define BR  16

// ws layout (bytes) — hi-only packed B fragments
#define B0P_OFF 0
#define B0P_SZ  (K0T * NT0 * 1024)       // 229376
#define B1P_OFF (B0P_OFF + B0P_SZ)
#define B1P_SZ  (K1T * NT1 * 1024)       // 262144
#define BDP_OFF (B1P_OFF + B1P_SZ)       // 491520
#define BDP_SZ  (KDT * NTD * 1024)       // 20480
#define B0P_N (B0P_SZ / 2)               // 114688
#define B1P_N (B1P_SZ / 2)               // 131072
#define TOT_N ((B0P_SZ + B1P_SZ + BDP_SZ) / 2)   // 256000

typedef __attribute__((ext_vector_type(8))) short bfrag;
typedef __attribute__((ext_vector_type(4))) float ffrag;

#define MFMA(AC, AA, BB) \
  AC = __builtin_amdgcn_mfma_f32_16x16x32_bf16((AA), (BB), (AC), 0, 0, 0)

__device__ __forceinline__ unsigned short bf16rn(float f) {
  union { float f; unsigned int u; } cv; cv.f = f;
  unsigned int u = cv.u;
  u += 0x7FFFu + ((u >> 16) & 1u);   // round-to-nearest-even
  return (unsigned short)(u >> 16);
}
__device__ __forceinline__ float bf16tof(unsigned short h) {
  union { unsigned int u; float f; } cv; cv.u = ((unsigned int)h) << 16;
  return cv.f;
}
__device__ __forceinline__ float sigmoid_f(float v) {
  return __fdividef(1.f, 1.f + __expf(-v));
}
__device__ __forceinline__ float tanh_f(float v) {
  float av = fabsf(v);
  float e  = __expf(-2.f * av);
  float t  = __fdividef(1.f - e, 1.f + e);
  return copysignf(t, v);
}

// ---------------- prep: pack hi-only weights in MFMA fragment order ---------
__global__ void wm_prep(
    const float* __restrict__ Wih0, const float* __restrict__ Whh0,
    const float* __restrict__ Wih1, const float* __restrict__ Whh1,
    const float* __restrict__ Wd,
    unsigned short* __restrict__ wsu)
{
  const int idx = blockIdx.x * 256 + threadIdx.x;
  if (idx >= TOT_N) return;
  int region, l;
  if (idx < B0P_N)               { region = 0; l = idx; }
  else if (idx < B0P_N + B1P_N)  { region = 1; l = idx - B0P_N; }
  else                           { region = 2; l = idx - (B0P_N + B1P_N); }

  int k, nt, lane, j;
  if (region < 2) {
    k  = l >> 14;            // 32 tiles * 512 ushorts = 16384 per ktile
    int r1 = l & 16383;
    nt = r1 >> 9;
    int li = r1 & 511;
    lane = li >> 3; j = li & 7;
  } else {
    k  = l / 2560;           // 5 * 512 per ktile
    int r1 = l % 2560;
    nt = r1 >> 9;
    int li = r1 & 511;
    lane = li >> 3; j = li & 7;
  }
  const int n  = nt * 16 + (lane & 15);
  const int kk = k * 32 + (lane >> 4) * 8 + j;

  float v = 0.f;
  if (region == 0) {
    if (kk < IN_)                    v = Wih0[n * IN_ + kk];
    else if (kk >= 96 && kk < 224)   v = Whh0[n * H_ + (kk - 96)];
  } else if (region == 1) {
    v = (kk < H_) ? Wih1[n * H_ + kk] : Whh1[n * H_ + (kk - H_)];
  } else {
    if (n < OUT_)                    v = Wd[n * H_ + kk];
  }
  wsu[idx] = bf16rn(v);
}

// ---------------- main persistent-recurrence kernel --------------------------
__global__ __launch_bounds__(512, 4) void wm_main(
    const float* __restrict__ x,
    const char*  __restrict__ wsb,
    const float* __restrict__ bih0, const float* __restrict__ bhh0,
    const float* __restrict__ bih1, const float* __restrict__ bhh1,
    const float* __restrict__ bd,
    float* __restrict__ out)
{
  __shared__ __align__(16) unsigned short A0h[BR * S0];
  __shared__ __align__(16) unsigned short A0l[BR * S0];
  __shared__ __align__(16) unsigned short A1h[BR * S1];
  __shared__ __align__(16) unsigned short A1l[BR * S1];

  const int tid  = threadIdx.x;
  const int lane = tid & 63;
  const int wv   = tid >> 6;      // wave id = unit-slice id (0..7)
  const int ln15 = lane & 15;
  const int quad = lane >> 4;
  const int lane16 = lane * 16;

  const char* B0 = wsb + B0P_OFF;
  const char* B1 = wsb + B1P_OFF;
  const char* BD = wsb + BDP_OFF;

  // zero LDS (h/c zero-init; A0 pads [86,96) and [224,232) stay zero)
  for (int i = tid; i < BR * S0; i += 512) { A0h[i] = 0; A0l[i] = 0; }
  for (int i = tid; i < BR * S1; i += 512) { A1h[i] = 0; A1l[i] = 0; }

  // bias preload — this wave's unit col = wv*16 + ln15, per gate g
  float b0r[4], b1r[4];
  #pragma unroll
  for (int g = 0; g < 4; ++g) {
    const int n = g * 128 + wv * 16 + ln15;
    b0r[g] = bih0[n] + bhh0[n];
    b1r[g] = bih1[n] + bhh1[n];
  }
  // dense head: waves 0..4 own o-tile wv (o = wv*16 + ln15)
  const int od = wv * 16 + ln15;
  const float bdr = (wv < NTD && od < OUT_) ? bd[od] : 0.f;

  float c1[4], c2[4];
  #pragma unroll
  for (int r = 0; r < 4; ++r) { c1[r] = 0.f; c2[r] = 0.f; }

  const int a0b = ln15 * S0 + quad * 8;    // A-frag offset (row ln15)
  const int a1b = ln15 * S1 + quad * 8;
  const int prow = quad * 4;               // C/D rows = prow + r
  const int unit = wv * 16 + ln15;         // this lane's unit column

  __syncthreads();

  for (int t = 0; t < 65; ++t) {
    // ---- input staging: t<50 from x; t==50 reuses x[:,49,:]; t>50 pose+cond
    if (t < T_) {
      const int r  = tid >> 5;             // 16 rows x 32 lanes
      const int kk = tid & 31;
      const float* xr = x + ((size_t)(blockIdx.x * BR + r) * T_ + t) * IN_;
      for (int k = kk; k < IN_; k += 32) {
        const float v = xr[k];
        const unsigned short hi = bf16rn(v);
        A0h[r * S0 + k] = hi;
        A0l[r * S0 + k] = bf16rn(v - bf16tof(hi));
      }
    }
    __syncthreads();   // (A) input/pose visible

    // ---- layer 0 GEMM: gates0 = [u|h1] x W0hi^T  (acc init = bias)
    ffrag acc0[4];
    #pragma unroll
    for (int g = 0; g < 4; ++g)
      acc0[g] = (ffrag){b0r[g], b0r[g], b0r[g], b0r[g]};
    #pragma unroll 2
    for (int k = 0; k < K0T; ++k) {
      const bfrag ah = *(const bfrag*)(A0h + a0b + k * 32);
      const bfrag al = *(const bfrag*)(A0l + a0b + k * 32);
      #pragma unroll
      for (int g = 0; g < 4; ++g) {
        const bfrag bh =
            *(const bfrag*)(B0 + (size_t)(k * NT0 + g * 8 + wv) * 1024 + lane16);
        MFMA(acc0[g], ah, bh);
        MFMA(acc0[g], al, bh);
      }
    }
    __syncthreads();   // (B) all waves done reading A0

    // ---- layer 0 pointwise: all 4 gates in-lane; write h1 hi/lo
    #pragma unroll
    for (int r = 0; r < 4; ++r) {
      const float ig = sigmoid_f(acc0[0][r]);
      const float fg = sigmoid_f(acc0[1][r]);
      const float gg = tanh_f(acc0[2][r]);
      const float og = sigmoid_f(acc0[3][r]);
      const float c  = fmaf(fg, c1[r], ig * gg);
      c1[r] = c;
      const float h  = og * tanh_f(c);
      const unsigned short hi = bf16rn(h);
      const unsigned short lo = bf16rn(h - bf16tof(hi));
      const int row = prow + r;
      A0h[row * S0 + 96 + unit] = hi;  A0l[row * S0 + 96 + unit] = lo;
      A1h[row * S1 + unit]      = hi;  A1l[row * S1 + unit]      = lo;
    }
    __syncthreads();   // (C) h1 visible

    // ---- layer 1 GEMM: gates1 = [h1|h2] x W1hi^T
    ffrag acc1[4];
    #pragma unroll
    for (int g = 0; g < 4; ++g)
      acc1[g] = (ffrag){b1r[g], b1r[g], b1r[g], b1r[g]};
    #pragma unroll 2
    for (int k = 0; k < K1T; ++k) {
      const bfrag ah = *(const bfrag*)(A1h + a1b + k * 32);
      const bfrag al = *(const bfrag*)(A1l + a1b + k * 32);
      #pragma unroll
      for (int g = 0; g < 4; ++g) {
        const bfrag bh =
            *(const bfrag*)(B1 + (size_t)(k * NT1 + g * 8 + wv) * 1024 + lane16);
        MFMA(acc1[g], ah, bh);
        MFMA(acc1[g], al, bh);
      }
    }
    __syncthreads();   // (D) all waves done reading A1 (old h2)

    // ---- layer 1 pointwise: write h2 hi/lo
    #pragma unroll
    for (int r = 0; r < 4; ++r) {
      const float ig = sigmoid_f(acc1[0][r]);
      const float fg = sigmoid_f(acc1[1][r]);
      const float gg = tanh_f(acc1[2][r]);
      const float og = sigmoid_f(acc1[3][r]);
      const float c  = fmaf(fg, c2[r], ig * gg);
      c2[r] = c;
      const float h  = og * tanh_f(c);
      const unsigned short hi = bf16rn(h);
      const unsigned short lo = bf16rn(h - bf16tof(hi));
      const int row = prow + r;
      A1h[row * S1 + 128 + unit] = hi;  A1l[row * S1 + 128 + unit] = lo;
    }

    // ---- dense head + pose feedback (t >= 50)
    if (t >= T_) {
      __syncthreads();   // (E) new h2 visible
      const int s = t - T_;
      if (wv < NTD) {
        ffrag dacc = (ffrag){bdr, bdr, bdr, bdr};
        #pragma unroll
        for (int k = 0; k < KDT; ++k) {
          const bfrag ah = *(const bfrag*)(A1h + a1b + 128 + k * 32);
          const bfrag al = *(const bfrag*)(A1l + a1b + 128 + k * 32);
          const bfrag bh =
              *(const bfrag*)(BD + (size_t)(k * NTD + wv) * 1024 + lane16);
          MFMA(dacc, ah, bh);
          MFMA(dacc, al, bh);
        }
        if (od < OUT_) {
          #pragma unroll
          for (int r = 0; r < 4; ++r) {
            const int row = prow + r;
            const float v = dacc[r];
            out[((size_t)(blockIdx.x * BR + row) * NPOSE + s) * OUT_ + od] = v;
            if (s < NPOSE - 1) {
              const unsigned short hi = bf16rn(v);
              A0h[row * S0 + od] = hi;
              A0l[row * S0 + od] = bf16rn(v - bf16tof(hi));
            }
          }
        }
      }
    }
    __syncthreads();   // (F) pose/h2 writes settle before next iter
  }
}

extern "C" void kernel_launch(void* const* d_in, const int* in_sizes, int n_in,
                              void* d_out, int out_size, void* d_ws, size_t ws_size,
                              hipStream_t stream)
{
  const float* x    = (const float*)d_in[0];
  const float* Wih0 = (const float*)d_in[1];
  const float* Whh0 = (const float*)d_in[2];
  const float* bih0 = (const float*)d_in[3];
  const float* bhh0 = (const float*)d_in[4];
  const float* Wih1 = (const float*)d_in[5];
  const float* Whh1 = (const float*)d_in[6];
  const float* bih1 = (const float*)d_in[7];
  const float* bhh1 = (const float*)d_in[8];
  const float* Wd   = (const float*)d_in[9];
  const float* bd   = (const float*)d_in[10];

  wm_prep<<<(TOT_N + 255) / 256, 256, 0, stream>>>(Wih0, Whh0, Wih1, Whh1, Wd,
                                                   (unsigned short*)d_ws);
  wm_main<<<B_ / BR, 512, 0, stream>>>(x, (const char*)d_ws,
                                       bih0, bhh0, bih1, bhh1, bd,
                                       (float*)d_out);
}